// Round 2
// baseline (269.623 us; speedup 1.0000x reference)
//
#include <hip/hip_runtime.h>

#define NB 32768   // batch rows

typedef short s8v __attribute__((ext_vector_type(8)));   // 8 x bf16 (bit pattern)
typedef float f4v __attribute__((ext_vector_type(4)));
typedef unsigned short u16;
typedef unsigned int u32;

__device__ __forceinline__ float bf2f(u16 u) { return __uint_as_float(((u32)u) << 16); }
__device__ __forceinline__ u16 f2bf(float f) {
    u32 x = __float_as_uint(f);
    x += 0x7FFFu + ((x >> 16) & 1u);   // round-to-nearest-even
    return (u16)(x >> 16);
}
__device__ __forceinline__ s8v ld8(const u16* p) { return *reinterpret_cast<const s8v*>(p); }

#define MFMA16(a, b, c) __builtin_amdgcn_mfma_f32_16x16x32_bf16((a), (b), (c), 0, 0, 0)

// ---------------------------------------------------------------------------
// probe: decide whether storage is bf16 (flag=1) or f32 (flag=0).
// Low 16 bits of each dword of row-0 feats: bf16 value (exponent in-range) if
// bf16 storage; uniform mantissa bits if f32 storage.
// ---------------------------------------------------------------------------
__global__ void probe_kernel(const void* __restrict__ input, int* __restrict__ flagp)
{
    int lane = threadIdx.x;
    u32 w = ((const u32*)input)[lane];          // both views: row-0 feats
    u32 h0 = w & 0xFFFFu;
    u32 e0 = (h0 >> 7) & 0xFFu;
    bool plaus = (h0 == 0u) || (e0 >= 96u && e0 <= 143u);
    unsigned long long m = __ballot(plaus);
    if (lane == 0) *flagp = (__popcll(m) >= 48) ? 1 : 0;
}

// ---------------------------------------------------------------------------
// prep kernel: blocks [0,128) bucket rows by (node, module); blocks [128,...)
// repack weights into MFMA B-fragment order [m][s][ct][lane][8], copy biases
// (+Wfin/bfin) to bf16 ws copies, and (f32 path only) convert input to bf16.
// ---------------------------------------------------------------------------
struct Ent { const void* src; u16* dst; int Ksrc; int kBase; int S; };
struct RepackArgs { Ent d[11]; };
struct BEnt { const void* src; int dstOff; int n; };
struct BiasArgs { BEnt d[10]; };

__global__ __launch_bounds__(256) void prep_kernel(const void* __restrict__ inputv,
                                                   const int* __restrict__ flagp,
                                                   int* __restrict__ counters,
                                                   int* __restrict__ perm,
                                                   u16* __restrict__ inB,
                                                   u16* __restrict__ cbias,
                                                   RepackArgs A, BiasArgs BA)
{
    int flag = *flagp;
    if (blockIdx.x < 128) {
        __shared__ int lcnt[16];
        __shared__ int lbase[16];
        int tid = threadIdx.x;
        int row = (blockIdx.x << 8) + tid;            // 128*256 == NB exactly
        if (tid < 16) lcnt[tid] = 0;
        __syncthreads();
        const u32* in32 = (const u32*)inputv;
        const u16* in16 = (const u16*)inputv;
        int mods[4], loc[4];
#pragma unroll
        for (int j = 0; j < 4; j++) {
            int base = row * 144 + 128 + j * 4;
            u32 v1, v2, v3;
            if (flag) { v1 = in16[base + 1]; v2 = in16[base + 2]; v3 = in16[base + 3]; }
            else      { v1 = in32[base + 1]; v2 = in32[base + 2]; v3 = in32[base + 3]; }
            int m = v1 ? 1 : (v2 ? 2 : (v3 ? 3 : 0));
            mods[j] = m;
            loc[j] = atomicAdd(&lcnt[j * 4 + m], 1);
        }
        __syncthreads();
        if (tid < 16) lbase[tid] = atomicAdd(&counters[tid], lcnt[tid]);
        __syncthreads();
#pragma unroll
        for (int j = 0; j < 4; j++) {
            int slot = j * 4 + mods[j];
            perm[slot * NB + lbase[slot] + loc[j]] = row;
        }
    } else {
        const int RTOT = 131072 + 7 * 262144;   // repack elements
        const int BTOT = 8 * 1024 + 8192 + 32;  // bias/Wfin/bfin elements
        const int PHA = RTOT + BTOT;
        int gtid = (blockIdx.x - 128) * 256 + threadIdx.x;
        int gstr = (gridDim.x - 128) * 256;
        int TOT = flag ? PHA : PHA + NB * 144;
        for (int i = gtid; i < TOT; i += gstr) {
            if (i < RTOT) {
                int e, local;
                if (i < 131072) { e = i >> 15; local = i & 32767; }
                else { int t = i - 131072; e = 4 + (t >> 18); local = t & 262143; }
                Ent d = A.d[e];
                int jj = local & 7, lane = (local >> 3) & 63, ct = (local >> 9) & 15;
                int m, s;
                if (d.S == 1) { m = local >> 13; s = 0; }
                else          { m = local >> 16; s = (local >> 13) & 7; }
                int k = d.kBase + s * 32 + ((lane >> 4) << 3) + jj;
                int n = (ct << 4) + (lane & 15);
                int idx = (m * d.Ksrc + k) * 256 + n;
                d.dst[local] = flag ? ((const u16*)d.src)[idx]
                                    : f2bf(((const float*)d.src)[idx]);
            } else if (i < PHA) {
                int t = i - RTOT;
                for (int e = 0; e < 10; e++) {
                    BEnt b = BA.d[e];
                    if (t < b.n) {
                        cbias[b.dstOff + t] = flag ? ((const u16*)b.src)[t]
                                                   : f2bf(((const float*)b.src)[t]);
                        break;
                    }
                    t -= b.n;
                }
            } else {
                int t = i - PHA;
                inB[t] = f2bf(((const float*)inputv)[t]);
            }
        }
    }
}

// ---------------------------------------------------------------------------
// node kernel: one block = 64 rows of one (module) bucket x 256 output cols.
//   hp = relu(feat_j @ Wpre[m] + bpre[m])                (K=32, into LDS)
//   hq = relu(x_prev @ WA[m] + hp @ WB[m] + bpost[m])    (K=512 MFMA)
//   node3: out = hq @ Wfin[m] + bfin[m]                  (LDS dot epilogue)
// ---------------------------------------------------------------------------
__global__ __launch_bounds__(256) void node_kernel(
    const void* __restrict__ inRaw, const u16* __restrict__ inB,
    const int* __restrict__ flagp,
    const int* __restrict__ perm4, const int* __restrict__ counts4,
    const u16* __restrict__ Rpre, const u16* __restrict__ bpre,
    const u16* __restrict__ RA,   const u16* __restrict__ RB,
    const u16* __restrict__ bpost,
    const u16* __restrict__ xprev, u16* __restrict__ xout,
    const u16* __restrict__ Wfin, const u16* __restrict__ bfin,
    void* __restrict__ outp, int featOff)
{
    __shared__ __align__(16) u16 hp[64 * 264];    // +8 pad: 2-way LDS conflicts only (free)
    __shared__ __align__(16) u16 wfl[8 * 264];    // Wfin transposed [o][k]
    __shared__ int rowids[64];

    int tid = threadIdx.x;
    int lane = tid & 63, w = tid >> 6, quad = lane >> 4, l16 = lane & 15;

    int flag = *flagp;
    const u16* ip = flag ? (const u16*)inRaw : inB;   // bf16 feats, stride 144

    // map block -> (module, tile); harden against garbage counts
    int c0 = counts4[0], c1 = counts4[1], c2 = counts4[2], c3 = counts4[3];
    if ((u32)c0 > NB) c0 = 0; if ((u32)c1 > NB) c1 = 0;
    if ((u32)c2 > NB) c2 = 0; if ((u32)c3 > NB) c3 = 0;
    int t0 = (c0 + 63) >> 6, t1 = (c1 + 63) >> 6, t2 = (c2 + 63) >> 6;
    int b = blockIdx.x;
    int mod, tile, cnt;
    if (b < t0)                { mod = 0; tile = b;             cnt = c0; }
    else if (b < t0 + t1)      { mod = 1; tile = b - t0;        cnt = c1; }
    else if (b < t0 + t1 + t2) { mod = 2; tile = b - t0 - t1;   cnt = c2; }
    else {
        int t3 = (c3 + 63) >> 6;
        if (b < t0 + t1 + t2 + t3) { mod = 3; tile = b - t0 - t1 - t2; cnt = c3; }
        else return;
    }
    int rbase = tile << 6;
    int cnt_in = cnt - rbase; if (cnt_in > 64) cnt_in = 64;

    if (tid < 64) {
        int g = rbase + tid; if (g > cnt - 1) g = cnt - 1;   // clamp partial tile
        u32 r = (u32)perm4[mod * NB + g];
        if (r >= NB) r = 0;                                  // harden wild rowids
        rowids[tid] = (int)r;
    }
    if (Wfin) {
#pragma unroll
        for (int o = 0; o < 8; o++) wfl[o * 264 + tid] = Wfin[((mod << 8) + tid) * 8 + o];
    }
    __syncthreads();

    // ---- hp stage: wave w computes row-tile w (16 rows) x 256 cols, K=32
    {
        int row = rowids[(w << 4) + l16];
        s8v a = ld8(ip + row * 144 + featOff + (quad << 3));
        const s8v* Bp = reinterpret_cast<const s8v*>(Rpre) + (mod << 4) * 64 + lane;
#pragma unroll
        for (int ct = 0; ct < 16; ct++) {
            f4v c = {0.f, 0.f, 0.f, 0.f};
            c = MFMA16(a, Bp[ct * 64], c);
            float bv = bf2f(bpre[(mod << 8) + (ct << 4) + l16]);
#pragma unroll
            for (int r = 0; r < 4; r++) {
                float v = c[r] + bv; v = v > 0.f ? v : 0.f;
                hp[((w << 4) + (quad << 2) + r) * 264 + (ct << 4) + l16] = f2bf(v);
            }
        }
    }
    __syncthreads();

    // ---- main GEMM: all 64 rows x cols [w*64, w*64+64)
    f4v acc[4][4];
#pragma unroll
    for (int i = 0; i < 4; i++)
#pragma unroll
        for (int j = 0; j < 4; j++) acc[i][j] = (f4v){0.f, 0.f, 0.f, 0.f};

    int row0 = rowids[l16], row1 = rowids[16 + l16], row2 = rowids[32 + l16], row3 = rowids[48 + l16];

    if (xprev) {
#pragma unroll
        for (int s = 0; s < 8; s++) {
            s8v a0 = ld8(xprev + (row0 << 8) + (s << 5) + (quad << 3));
            s8v a1 = ld8(xprev + (row1 << 8) + (s << 5) + (quad << 3));
            s8v a2 = ld8(xprev + (row2 << 8) + (s << 5) + (quad << 3));
            s8v a3 = ld8(xprev + (row3 << 8) + (s << 5) + (quad << 3));
            const s8v* Bp = reinterpret_cast<const s8v*>(RA) + ((((mod << 3) + s) << 4) + (w << 2)) * 64 + lane;
#pragma unroll
            for (int ci = 0; ci < 4; ci++) {
                s8v bv = Bp[ci * 64];
                acc[0][ci] = MFMA16(a0, bv, acc[0][ci]);
                acc[1][ci] = MFMA16(a1, bv, acc[1][ci]);
                acc[2][ci] = MFMA16(a2, bv, acc[2][ci]);
                acc[3][ci] = MFMA16(a3, bv, acc[3][ci]);
            }
        }
    }
#pragma unroll
    for (int s = 0; s < 8; s++) {
        s8v a0 = ld8(&hp[(l16) * 264 + (s << 5) + (quad << 3)]);
        s8v a1 = ld8(&hp[(16 + l16) * 264 + (s << 5) + (quad << 3)]);
        s8v a2 = ld8(&hp[(32 + l16) * 264 + (s << 5) + (quad << 3)]);
        s8v a3 = ld8(&hp[(48 + l16) * 264 + (s << 5) + (quad << 3)]);
        const s8v* Bp = reinterpret_cast<const s8v*>(RB) + ((((mod << 3) + s) << 4) + (w << 2)) * 64 + lane;
#pragma unroll
        for (int ci = 0; ci < 4; ci++) {
            s8v bv = Bp[ci * 64];
            acc[0][ci] = MFMA16(a0, bv, acc[0][ci]);
            acc[1][ci] = MFMA16(a1, bv, acc[1][ci]);
            acc[2][ci] = MFMA16(a2, bv, acc[2][ci]);
            acc[3][ci] = MFMA16(a3, bv, acc[3][ci]);
        }
    }

    if (!outp) {
        // bias + relu + scatter to x_out (bf16), masked for partial tiles
#pragma unroll
        for (int ci = 0; ci < 4; ci++) {
            int col = (((w << 2) + ci) << 4) + l16;
            float bv = bf2f(bpost[(mod << 8) + col]);
#pragma unroll
            for (int rt = 0; rt < 4; rt++) {
#pragma unroll
                for (int r = 0; r < 4; r++) {
                    int local = (rt << 4) + (quad << 2) + r;
                    float v = acc[rt][ci][r] + bv; v = v > 0.f ? v : 0.f;
                    if (local < cnt_in) xout[(rowids[local] << 8) + col] = f2bf(v);
                }
            }
        }
    } else {
        __syncthreads();   // all waves done reading hp before overwriting with hq
#pragma unroll
        for (int ci = 0; ci < 4; ci++) {
            int col = (((w << 2) + ci) << 4) + l16;
            float bv = bf2f(bpost[(mod << 8) + col]);
#pragma unroll
            for (int rt = 0; rt < 4; rt++) {
#pragma unroll
                for (int r = 0; r < 4; r++) {
                    int local = (rt << 4) + (quad << 2) + r;
                    float v = acc[rt][ci][r] + bv; v = v > 0.f ? v : 0.f;
                    hp[local * 264 + col] = f2bf(v);
                }
            }
        }
        __syncthreads();
        // final 256->8 linear (identity act): 512 (row,out) pairs over 256 threads
#pragma unroll
        for (int p = 0; p < 2; p++) {
            int pid = tid + (p << 8);
            int r = pid >> 3, o = pid & 7;
            float s = bf2f(bfin[(mod << 3) + o]);
            const u16* hrow = &hp[r * 264];
            const u16* wrow = &wfl[o * 264];
            for (int k = 0; k < 256; k += 8) {
                s8v h8 = ld8(hrow + k);
                s8v w8 = ld8(wrow + k);
#pragma unroll
                for (int j = 0; j < 8; j++) s += bf2f((u16)h8[j]) * bf2f((u16)w8[j]);
            }
            if (r < cnt_in) {
                int oi = (rowids[r] << 3) + o;
                if (flag) ((u16*)outp)[oi] = f2bf(s);
                else      ((float*)outp)[oi] = s;
            }
        }
    }
}

// ---------------------------------------------------------------------------
extern "C" void kernel_launch(void* const* d_in, const int* in_sizes, int n_in,
                              void* d_out, int out_size, void* d_ws, size_t ws_size,
                              hipStream_t stream)
{
    (void)in_sizes; (void)n_in; (void)out_size;
    const void* input = d_in[0];
    const void* W00    = d_in[1];
    const void* b00    = d_in[2];
    const void* W01    = d_in[3];
    const void* b01    = d_in[4];
    const void* Wpre1  = d_in[5];
    const void* bpre1  = d_in[6];
    const void* Wpost1 = d_in[7];
    const void* bpost1 = d_in[8];
    const void* Wpre2  = d_in[9];
    const void* bpre2  = d_in[10];
    const void* Wpost2 = d_in[11];
    const void* bpost2 = d_in[12];
    const void* Wpre3  = d_in[13];
    const void* bpre3  = d_in[14];
    const void* Wpost3 = d_in[15];
    const void* bpost3 = d_in[16];
    const void* Wfin   = d_in[17];
    const void* bfin   = d_in[18];

    char* base = (char*)d_ws;
    size_t off = 0;
    auto alloc = [&](size_t bytes) -> char* {
        char* p = base + off;
        off += (bytes + 255) & ~(size_t)255;
        return p;
    };
    int* flagp    = (int*)alloc(4);
    int* counters = (int*)alloc(64);                           // [4 nodes][4 mods]
    u16* cbias    = (u16*)alloc(16640 * 2);                    // biases + Wfin + bfin (bf16)
    int* perm     = (int*)alloc((size_t)16 * NB * 4);          // [4][4][NB]
    u16* x0 = (u16*)alloc((size_t)NB * 256 * 2);
    u16* x1 = (u16*)alloc((size_t)NB * 256 * 2);
    u16* inB = (u16*)alloc((size_t)NB * 144 * 2);              // bf16 input copy (f32 path)
    u16* rW00   = (u16*)alloc(32768 * 2);
    u16* rWpre1 = (u16*)alloc(32768 * 2);
    u16* rWpre2 = (u16*)alloc(32768 * 2);
    u16* rWpre3 = (u16*)alloc(32768 * 2);
    u16* rW01 = (u16*)alloc(262144 * 2);
    u16* rW1A = (u16*)alloc(262144 * 2);
    u16* rW1B = (u16*)alloc(262144 * 2);
    u16* rW2A = (u16*)alloc(262144 * 2);
    u16* rW2B = (u16*)alloc(262144 * 2);
    u16* rW3A = (u16*)alloc(262144 * 2);
    u16* rW3B = (u16*)alloc(262144 * 2);
    if (off > ws_size) return;   // ws too small: bail without corrupting memory

    hipMemsetAsync(counters, 0, 64, stream);
    probe_kernel<<<1, 64, 0, stream>>>(input, flagp);

    RepackArgs ra;
    ra.d[0]  = Ent{W00,    rW00,   32,   0, 1};
    ra.d[1]  = Ent{Wpre1,  rWpre1, 32,   0, 1};
    ra.d[2]  = Ent{Wpre2,  rWpre2, 32,   0, 1};
    ra.d[3]  = Ent{Wpre3,  rWpre3, 32,   0, 1};
    ra.d[4]  = Ent{W01,    rW01,  256,   0, 8};
    ra.d[5]  = Ent{Wpost1, rW1A,  512,   0, 8};
    ra.d[6]  = Ent{Wpost1, rW1B,  512, 256, 8};
    ra.d[7]  = Ent{Wpost2, rW2A,  512,   0, 8};
    ra.d[8]  = Ent{Wpost2, rW2B,  512, 256, 8};
    ra.d[9]  = Ent{Wpost3, rW3A,  512,   0, 8};
    ra.d[10] = Ent{Wpost3, rW3B,  512, 256, 8};

    BiasArgs ba;
    ba.d[0] = BEnt{b00,    0,     1024};
    ba.d[1] = BEnt{b01,    1024,  1024};
    ba.d[2] = BEnt{bpre1,  2048,  1024};
    ba.d[3] = BEnt{bpost1, 3072,  1024};
    ba.d[4] = BEnt{bpre2,  4096,  1024};
    ba.d[5] = BEnt{bpost2, 5120,  1024};
    ba.d[6] = BEnt{bpre3,  6144,  1024};
    ba.d[7] = BEnt{bpost3, 7168,  1024};
    ba.d[8] = BEnt{Wfin,   8192,  8192};
    ba.d[9] = BEnt{bfin,   16384, 32};

    prep_kernel<<<128 + 1536, 256, 0, stream>>>(input, flagp, counters, perm, inB, cbias, ra, ba);

    // node 0: hp = relu(feat0@W00+b00); x0 = relu(hp@W01+b01)
    node_kernel<<<516, 256, 0, stream>>>(input, inB, flagp, perm,           counters,
                                         rW00,   cbias + 0,    nullptr, rW01, cbias + 1024,
                                         nullptr, x0, nullptr, nullptr, nullptr, 0);
    // node 1
    node_kernel<<<516, 256, 0, stream>>>(input, inB, flagp, perm + 4 * NB,  counters + 4,
                                         rWpre1, cbias + 2048, rW1A, rW1B, cbias + 3072,
                                         x0, x1, nullptr, nullptr, nullptr, 32);
    // node 2
    node_kernel<<<516, 256, 0, stream>>>(input, inB, flagp, perm + 8 * NB,  counters + 8,
                                         rWpre2, cbias + 4096, rW2A, rW2B, cbias + 5120,
                                         x1, x0, nullptr, nullptr, nullptr, 64);
    // node 3 (+ final 256->8 linear to d_out)
    node_kernel<<<516, 256, 0, stream>>>(input, inB, flagp, perm + 12 * NB, counters + 12,
                                         rWpre3, cbias + 6144, rW3A, rW3B, cbias + 7168,
                                         x0, nullptr, cbias + 8192, cbias + 16384, d_out, 96);
}

// Round 3
// 203.699 us; speedup vs baseline: 1.3236x; 1.3236x over previous
//
#include <hip/hip_runtime.h>

#define NB 32768        // batch rows
#define MAXTILE 768     // max row-tiles: 256 keys + NB/64

typedef short s8v __attribute__((ext_vector_type(8)));   // 8 x bf16 (bit pattern)
typedef float f4v __attribute__((ext_vector_type(4)));
typedef unsigned short u16;
typedef unsigned int u32;
typedef unsigned char u8;

__device__ __forceinline__ float bf2f(u16 u) { return __uint_as_float(((u32)u) << 16); }
__device__ __forceinline__ u16 f2bf(float f) {
    u32 x = __float_as_uint(f);
    x += 0x7FFFu + ((x >> 16) & 1u);   // round-to-nearest-even
    return (u16)(x >> 16);
}
__device__ __forceinline__ s8v ld8(const u16* p) { return *reinterpret_cast<const s8v*>(p); }

#define MFMA16(a, b, c) __builtin_amdgcn_mfma_f32_16x16x32_bf16((a), (b), (c), 0, 0, 0)

// ---------------------------------------------------------------------------
// probe: storage dtype detect — bf16 (flag=1) vs f32 (flag=0).
// ---------------------------------------------------------------------------
__global__ void probe_kernel(const void* __restrict__ input, int* __restrict__ flagp)
{
    int lane = threadIdx.x;
    u32 w = ((const u32*)input)[lane];
    u32 h0 = w & 0xFFFFu;
    u32 e0 = (h0 >> 7) & 0xFFu;
    bool plaus = (h0 == 0u) || (e0 >= 96u && e0 <= 143u);
    unsigned long long m = __ballot(plaus);
    if (lane == 0) *flagp = (__popcll(m) >= 48) ? 1 : 0;
}

// ---------------------------------------------------------------------------
// prepA: blocks [0,128) compute 8-bit key per row + count histogram;
// blocks [128,...) repack weights to MFMA B-frag order, biases->bf16, input->bf16.
// ---------------------------------------------------------------------------
struct Ent { const void* src; u16* dst; int Ksrc; int kBase; int S; };
struct RepackArgs { Ent d[11]; };
struct BEnt { const void* src; int dstOff; int n; };
struct BiasArgs { BEnt d[10]; };

__global__ __launch_bounds__(256) void prepA_kernel(const void* __restrict__ inputv,
                                                    const int* __restrict__ flagp,
                                                    int* __restrict__ counters,
                                                    u8* __restrict__ keys,
                                                    u16* __restrict__ inB,
                                                    u16* __restrict__ cbias,
                                                    RepackArgs A, BiasArgs BA)
{
    int flag = *flagp;
    if (blockIdx.x < 128) {
        __shared__ int lcnt[256];
        int tid = threadIdx.x;
        lcnt[tid] = 0;
        __syncthreads();
        int row = (blockIdx.x << 8) + tid;
        const u32* in32 = (const u32*)inputv;
        const u16* in16 = (const u16*)inputv;
        int key = 0;
#pragma unroll
        for (int j = 0; j < 4; j++) {
            int base = row * 144 + 128 + j * 4;
            u32 v1, v2, v3;
            if (flag) { v1 = in16[base + 1]; v2 = in16[base + 2]; v3 = in16[base + 3]; }
            else      { v1 = in32[base + 1]; v2 = in32[base + 2]; v3 = in32[base + 3]; }
            int m = v1 ? 1 : (v2 ? 2 : (v3 ? 3 : 0));
            key |= m << (j << 1);
        }
        keys[row] = (u8)key;
        atomicAdd(&lcnt[key], 1);
        __syncthreads();
        if (lcnt[tid]) atomicAdd(&counters[tid], lcnt[tid]);
    } else {
        const int RTOT = 131072 + 7 * 262144;
        const int BTOT = 8 * 1024 + 8192 + 32;
        const int PHA = RTOT + BTOT;
        int gtid = (blockIdx.x - 128) * 256 + threadIdx.x;
        int gstr = (gridDim.x - 128) * 256;
        int TOT = flag ? PHA : PHA + NB * 144;
        for (int i = gtid; i < TOT; i += gstr) {
            if (i < RTOT) {
                int e, local;
                if (i < 131072) { e = i >> 15; local = i & 32767; }
                else { int t = i - 131072; e = 4 + (t >> 18); local = t & 262143; }
                Ent d = A.d[e];
                int jj = local & 7, lane = (local >> 3) & 63, ct = (local >> 9) & 15;
                int m, s;
                if (d.S == 1) { m = local >> 13; s = 0; }
                else          { m = local >> 16; s = (local >> 13) & 7; }
                int k = d.kBase + s * 32 + ((lane >> 4) << 3) + jj;
                int n = (ct << 4) + (lane & 15);
                int idx = (m * d.Ksrc + k) * 256 + n;
                d.dst[local] = flag ? ((const u16*)d.src)[idx]
                                    : f2bf(((const float*)d.src)[idx]);
            } else if (i < PHA) {
                int t = i - RTOT;
                for (int e = 0; e < 10; e++) {
                    BEnt b = BA.d[e];
                    if (t < b.n) {
                        cbias[b.dstOff + t] = flag ? ((const u16*)b.src)[t]
                                                   : f2bf(((const float*)b.src)[t]);
                        break;
                    }
                    t -= b.n;
                }
            } else {
                int t = i - PHA;
                inB[t] = f2bf(((const float*)inputv)[t]);
            }
        }
    }
}

// ---------------------------------------------------------------------------
// scan: 1 block. Exclusive scans of counts -> perm bases (cursors) and of
// ceil(count/64) -> tile table {key, permPos, rowsInTile}.
// ---------------------------------------------------------------------------
__global__ __launch_bounds__(256) void scan_kernel(const int* __restrict__ counters,
                                                   int* __restrict__ cursors,
                                                   int4* __restrict__ tileInfo)
{
    __shared__ int sbuf[256];
    __shared__ int tot;
    int tid = threadIdx.x;
    int c = counters[tid];
    sbuf[tid] = c;
    __syncthreads();
    for (int off = 1; off < 256; off <<= 1) {
        int v = (tid >= off) ? sbuf[tid - off] : 0;
        __syncthreads();
        sbuf[tid] += v;
        __syncthreads();
    }
    int base = sbuf[tid] - c;
    cursors[tid] = base;
    int tiles = (c + 63) >> 6;
    __syncthreads();
    sbuf[tid] = tiles;
    __syncthreads();
    for (int off = 1; off < 256; off <<= 1) {
        int v = (tid >= off) ? sbuf[tid - off] : 0;
        __syncthreads();
        sbuf[tid] += v;
        __syncthreads();
    }
    int tbase = sbuf[tid] - tiles;
    if (tid == 255) tot = sbuf[255];
    __syncthreads();
    for (int t = 0; t < tiles; t++) {
        int rem = c - t * 64;
        tileInfo[tbase + t] = make_int4(tid, base + t * 64, rem > 64 ? 64 : rem, 0);
    }
    for (int i = tot + tid; i < MAXTILE; i += 256)
        tileInfo[i] = make_int4(0, 0, 0, 0);
}

// ---------------------------------------------------------------------------
// prepB: scatter rows into perm (order within a key bucket irrelevant).
// ---------------------------------------------------------------------------
__global__ __launch_bounds__(256) void prepB_kernel(const u8* __restrict__ keys,
                                                    int* __restrict__ cursors,
                                                    int* __restrict__ perm)
{
    __shared__ int lcnt[256];
    __shared__ int lbase[256];
    int tid = threadIdx.x;
    lcnt[tid] = 0;
    __syncthreads();
    int row = (blockIdx.x << 8) + tid;
    int key = keys[row];
    int loc = atomicAdd(&lcnt[key], 1);
    __syncthreads();
    if (lcnt[tid]) lbase[tid] = atomicAdd(&cursors[tid], lcnt[tid]);
    __syncthreads();
    perm[lbase[key] + loc] = row;
}

// ---------------------------------------------------------------------------
// main: one block = 64 rows (one key tile) through the ENTIRE network.
// 8 waves; wave w owns 32 output cols. x and hp live in LDS; no global x.
// ---------------------------------------------------------------------------
struct MainW {
    const u16* pre[4];   // [m][ct][lane][8]   K=32
    const u16* A[4];     // [m][s][ct][lane][8]  (A[0] unused)
    const u16* B[4];     // [m][s][ct][lane][8]
    int bpre[4];         // cbias offsets, hp bias
    int bmain[4];        // cbias offsets, interface bias
};

__global__ __launch_bounds__(512, 4) void main_kernel(
    const void* __restrict__ inRaw, const u16* __restrict__ inB,
    const int* __restrict__ flagp,
    const int* __restrict__ perm, const int4* __restrict__ tileInfo,
    const u16* __restrict__ cbias, MainW W, void* __restrict__ outp)
{
    __shared__ __align__(16) u16 xc[64 * 264];
    __shared__ __align__(16) u16 hp[64 * 264];
    __shared__ __align__(16) u16 wfl[8 * 264];
    __shared__ int rowids[64];

    int tid = threadIdx.x;
    int lane = tid & 63, wave = tid >> 6, quad = lane >> 4, l16 = lane & 15;

    int4 ti = tileInfo[blockIdx.x];
    int key = ti.x, ppos = ti.y, cntIn = ti.z;
    if (cntIn <= 0) return;
    int flag = *flagp;
    const u16* ip = flag ? (const u16*)inRaw : inB;   // bf16 feats, stride 144

    if (tid < 64) {
        int g = tid < cntIn ? tid : cntIn - 1;   // clamp partial tile (dups benign)
        rowids[tid] = perm[ppos + g];
    }
    {
        int m3 = (key >> 6) & 3;
        const u16* Wf = cbias + 8192;            // [m][k][o]
        for (int i = tid; i < 2048; i += 512) {
            int k = i & 255, o = i >> 8;
            wfl[o * 264 + k] = Wf[(((m3 << 8) + k) << 3) + o];
        }
    }
    __syncthreads();

    int ct0 = wave << 1;

    for (int node = 0; node < 4; node++) {
        int m = (key >> (node << 1)) & 3;

        // ---- hp = relu(feat_node @ Wpre[m] + bpre[m])  (K=32), own 2 col-tiles
        {
            const s8v* Bp = (const s8v*)W.pre[node] + (m << 4) * 64 + lane;
            const u16* bb = cbias + W.bpre[node] + (m << 8);
#pragma unroll
            for (int rt = 0; rt < 4; rt++) {
                int row = rowids[(rt << 4) + l16];
                s8v a = ld8(ip + row * 144 + (node << 5) + (quad << 3));
#pragma unroll
                for (int ci = 0; ci < 2; ci++) {
                    int ct = ct0 + ci;
                    f4v c = {0.f, 0.f, 0.f, 0.f};
                    c = MFMA16(a, Bp[ct * 64], c);
                    float bv = bf2f(bb[(ct << 4) + l16]);
#pragma unroll
                    for (int r = 0; r < 4; r++) {
                        float v = c[r] + bv; v = v > 0.f ? v : 0.f;
                        hp[((rt << 4) + (quad << 2) + r) * 264 + (ct << 4) + l16] = f2bf(v);
                    }
                }
            }
        }
        __syncthreads();

        // ---- interface GEMM: acc = x_prev @ A[m] + hp @ B[m]   (K=256/512)
        f4v acc[4][2];
#pragma unroll
        for (int i = 0; i < 4; i++) { acc[i][0] = (f4v){0,0,0,0}; acc[i][1] = (f4v){0,0,0,0}; }

        if (node > 0) {
            const s8v* BA = (const s8v*)W.A[node];
#pragma unroll
            for (int s = 0; s < 8; s++) {
                s8v a0 = ld8(&xc[(l16) * 264 + (s << 5) + (quad << 3)]);
                s8v a1 = ld8(&xc[(16 + l16) * 264 + (s << 5) + (quad << 3)]);
                s8v a2 = ld8(&xc[(32 + l16) * 264 + (s << 5) + (quad << 3)]);
                s8v a3 = ld8(&xc[(48 + l16) * 264 + (s << 5) + (quad << 3)]);
#pragma unroll
                for (int ci = 0; ci < 2; ci++) {
                    s8v bv = BA[((((m << 3) + s) << 4) + ct0 + ci) * 64 + lane];
                    acc[0][ci] = MFMA16(a0, bv, acc[0][ci]);
                    acc[1][ci] = MFMA16(a1, bv, acc[1][ci]);
                    acc[2][ci] = MFMA16(a2, bv, acc[2][ci]);
                    acc[3][ci] = MFMA16(a3, bv, acc[3][ci]);
                }
            }
        }
        {
            const s8v* BB = (const s8v*)W.B[node];
#pragma unroll
            for (int s = 0; s < 8; s++) {
                s8v a0 = ld8(&hp[(l16) * 264 + (s << 5) + (quad << 3)]);
                s8v a1 = ld8(&hp[(16 + l16) * 264 + (s << 5) + (quad << 3)]);
                s8v a2 = ld8(&hp[(32 + l16) * 264 + (s << 5) + (quad << 3)]);
                s8v a3 = ld8(&hp[(48 + l16) * 264 + (s << 5) + (quad << 3)]);
#pragma unroll
                for (int ci = 0; ci < 2; ci++) {
                    s8v bv = BB[((((m << 3) + s) << 4) + ct0 + ci) * 64 + lane];
                    acc[0][ci] = MFMA16(a0, bv, acc[0][ci]);
                    acc[1][ci] = MFMA16(a1, bv, acc[1][ci]);
                    acc[2][ci] = MFMA16(a2, bv, acc[2][ci]);
                    acc[3][ci] = MFMA16(a3, bv, acc[3][ci]);
                }
            }
        }
        __syncthreads();   // all xc/hp reads complete before overwrite

        // ---- bias + relu -> xc (own 2 col-tiles, all 64 rows)
        {
            const u16* bm = cbias + W.bmain[node] + (m << 8);
#pragma unroll
            for (int ci = 0; ci < 2; ci++) {
                int colb = ((ct0 + ci) << 4) + l16;
                float bv = bf2f(bm[colb]);
#pragma unroll
                for (int rt = 0; rt < 4; rt++) {
#pragma unroll
                    for (int r = 0; r < 4; r++) {
                        float v = acc[rt][ci][r] + bv; v = v > 0.f ? v : 0.f;
                        xc[((rt << 4) + (quad << 2) + r) * 264 + colb] = f2bf(v);
                    }
                }
            }
        }
        __syncthreads();
    }

    // ---- final 256->8 linear: one (row, out) pair per thread
    {
        int m3 = (key >> 6) & 3;
        int r = tid >> 3, o = tid & 7;
        float s = bf2f(cbias[16384 + (m3 << 3) + o]);
        const u16* hrow = &xc[r * 264];
        const u16* wrow = &wfl[o * 264];
        for (int k = 0; k < 256; k += 8) {
            s8v h8 = ld8(hrow + k);
            s8v w8 = ld8(wrow + k);
#pragma unroll
            for (int j = 0; j < 8; j++) s += bf2f((u16)h8[j]) * bf2f((u16)w8[j]);
        }
        if (r < cntIn) {
            int oi = (rowids[r] << 3) + o;
            if (flag) ((u16*)outp)[oi] = f2bf(s);
            else      ((float*)outp)[oi] = s;
        }
    }
}

// ---------------------------------------------------------------------------
extern "C" void kernel_launch(void* const* d_in, const int* in_sizes, int n_in,
                              void* d_out, int out_size, void* d_ws, size_t ws_size,
                              hipStream_t stream)
{
    (void)in_sizes; (void)n_in; (void)out_size;
    const void* input  = d_in[0];
    const void* W00    = d_in[1];
    const void* b00    = d_in[2];
    const void* W01    = d_in[3];
    const void* b01    = d_in[4];
    const void* Wpre1  = d_in[5];
    const void* bpre1  = d_in[6];
    const void* Wpost1 = d_in[7];
    const void* bpost1 = d_in[8];
    const void* Wpre2  = d_in[9];
    const void* bpre2  = d_in[10];
    const void* Wpost2 = d_in[11];
    const void* bpost2 = d_in[12];
    const void* Wpre3  = d_in[13];
    const void* bpre3  = d_in[14];
    const void* Wpost3 = d_in[15];
    const void* bpost3 = d_in[16];
    const void* Wfin   = d_in[17];
    const void* bfin   = d_in[18];

    char* base = (char*)d_ws;
    size_t off = 0;
    auto alloc = [&](size_t bytes) -> char* {
        char* p = base + off;
        off += (bytes + 255) & ~(size_t)255;
        return p;
    };
    int*  flagp    = (int*)alloc(4);
    int*  counters = (int*)alloc(256 * 4);
    int*  cursors  = (int*)alloc(256 * 4);
    u8*   keys     = (u8*)alloc(NB);
    int4* tileInfo = (int4*)alloc(MAXTILE * 16);
    int*  perm     = (int*)alloc((size_t)NB * 4);
    u16*  cbias    = (u16*)alloc(16640 * 2);
    u16*  inB      = (u16*)alloc((size_t)NB * 144 * 2);
    u16* rW00   = (u16*)alloc(32768 * 2);
    u16* rWpre1 = (u16*)alloc(32768 * 2);
    u16* rWpre2 = (u16*)alloc(32768 * 2);
    u16* rWpre3 = (u16*)alloc(32768 * 2);
    u16* rW01 = (u16*)alloc(262144 * 2);
    u16* rW1A = (u16*)alloc(262144 * 2);
    u16* rW1B = (u16*)alloc(262144 * 2);
    u16* rW2A = (u16*)alloc(262144 * 2);
    u16* rW2B = (u16*)alloc(262144 * 2);
    u16* rW3A = (u16*)alloc(262144 * 2);
    u16* rW3B = (u16*)alloc(262144 * 2);
    if (off > ws_size) return;

    hipMemsetAsync(counters, 0, 256 * 4, stream);
    probe_kernel<<<1, 64, 0, stream>>>(input, flagp);

    RepackArgs ra;
    ra.d[0]  = Ent{W00,    rW00,   32,   0, 1};
    ra.d[1]  = Ent{Wpre1,  rWpre1, 32,   0, 1};
    ra.d[2]  = Ent{Wpre2,  rWpre2, 32,   0, 1};
    ra.d[3]  = Ent{Wpre3,  rWpre3, 32,   0, 1};
    ra.d[4]  = Ent{W01,    rW01,  256,   0, 8};
    ra.d[5]  = Ent{Wpost1, rW1A,  512,   0, 8};
    ra.d[6]  = Ent{Wpost1, rW1B,  512, 256, 8};
    ra.d[7]  = Ent{Wpost2, rW2A,  512,   0, 8};
    ra.d[8]  = Ent{Wpost2, rW2B,  512, 256, 8};
    ra.d[9]  = Ent{Wpost3, rW3A,  512,   0, 8};
    ra.d[10] = Ent{Wpost3, rW3B,  512, 256, 8};

    BiasArgs ba;
    ba.d[0] = BEnt{b00,    0,     1024};
    ba.d[1] = BEnt{b01,    1024,  1024};
    ba.d[2] = BEnt{bpre1,  2048,  1024};
    ba.d[3] = BEnt{bpost1, 3072,  1024};
    ba.d[4] = BEnt{bpre2,  4096,  1024};
    ba.d[5] = BEnt{bpost2, 5120,  1024};
    ba.d[6] = BEnt{bpre3,  6144,  1024};
    ba.d[7] = BEnt{bpost3, 7168,  1024};
    ba.d[8] = BEnt{Wfin,   8192,  8192};
    ba.d[9] = BEnt{bfin,   16384, 32};

    prepA_kernel<<<128 + 1536, 256, 0, stream>>>(input, flagp, counters, keys, inB, cbias, ra, ba);
    scan_kernel<<<1, 256, 0, stream>>>(counters, cursors, tileInfo);
    prepB_kernel<<<128, 256, 0, stream>>>(keys, cursors, perm);

    MainW W;
    W.pre[0] = rW00;   W.pre[1] = rWpre1; W.pre[2] = rWpre2; W.pre[3] = rWpre3;
    W.A[0]   = nullptr; W.A[1]  = rW1A;   W.A[2]   = rW2A;   W.A[3]   = rW3A;
    W.B[0]   = rW01;   W.B[1]   = rW1B;   W.B[2]   = rW2B;   W.B[3]   = rW3B;
    W.bpre[0] = 0;    W.bpre[1] = 2048; W.bpre[2] = 4096; W.bpre[3] = 6144;
    W.bmain[0] = 1024; W.bmain[1] = 3072; W.bmain[2] = 5120; W.bmain[3] = 7168;

    main_kernel<<<MAXTILE, 512, 0, stream>>>(input, inB, flagp, perm, tileInfo, cbias, W, d_out);
}

// Round 5
// 200.326 us; speedup vs baseline: 1.3459x; 1.0168x over previous
//
#include <hip/hip_runtime.h>

#define NB 32768
#define MAXTILE 768
#define XHS 536            // xh stride in u16: 1072 B, 268 dw ≡ 12 mod 32 → conflict-free

typedef short s8v __attribute__((ext_vector_type(8)));   // 8 x bf16 bits (4 VGPR)
typedef short s4v __attribute__((ext_vector_type(4)));   // 8 B LDS/global store
typedef float f4v __attribute__((ext_vector_type(4)));
typedef unsigned short u16;
typedef unsigned short u16x4 __attribute__((ext_vector_type(4)));
typedef unsigned int u32;
typedef unsigned char u8;

__device__ __forceinline__ float bf2f(u16 u) { return __uint_as_float(((u32)u) << 16); }
__device__ __forceinline__ u16 f2bf(float f) {
    u32 x = __float_as_uint(f);
    x += 0x7FFFu + ((x >> 16) & 1u);   // RNE
    return (u16)(x >> 16);
}
__device__ __forceinline__ s8v ld8(const u16* p) { return *reinterpret_cast<const s8v*>(p); }

#define MFMA16(a, b, c) __builtin_amdgcn_mfma_f32_16x16x32_bf16((a), (b), (c), 0, 0, 0)

// ---------------------------------------------------------------------------
// probe: zero counters + dtype flag (bf16=1 / f32=0) from low-half exponent stats
// ---------------------------------------------------------------------------
__global__ __launch_bounds__(256) void probe_kernel(const void* __restrict__ input,
                                                    int* __restrict__ flagp,
                                                    int* __restrict__ counters)
{
    int tid = threadIdx.x;
    counters[tid] = 0;
    if (tid < 64) {
        u32 w = ((const u32*)input)[tid];
        u32 h0 = w & 0xFFFFu;
        u32 e0 = (h0 >> 7) & 0xFFu;
        bool plaus = (h0 == 0u) || (e0 >= 96u && e0 <= 143u);
        unsigned long long m = __ballot(plaus);
        if (tid == 0) *flagp = (__popcll(m) >= 48) ? 1 : 0;
    }
}

// ---------------------------------------------------------------------------
// prepA: 8-bit key per row + histogram
// ---------------------------------------------------------------------------
__global__ __launch_bounds__(256) void prepA_kernel(const void* __restrict__ inputv,
                                                    const int* __restrict__ flagp,
                                                    int* __restrict__ counters,
                                                    u8* __restrict__ keys)
{
    __shared__ int lcnt[256];
    int flag = *flagp;
    int tid = threadIdx.x;
    lcnt[tid] = 0;
    __syncthreads();
    int row = (blockIdx.x << 8) + tid;
    const u32* in32 = (const u32*)inputv;
    const u16* in16 = (const u16*)inputv;
    int key = 0;
#pragma unroll
    for (int j = 0; j < 4; j++) {
        int base = row * 144 + 128 + j * 4;
        u32 v1, v2, v3;
        if (flag) { v1 = in16[base + 1]; v2 = in16[base + 2]; v3 = in16[base + 3]; }
        else      { v1 = in32[base + 1]; v2 = in32[base + 2]; v3 = in32[base + 3]; }
        int m = v1 ? 1 : (v2 ? 2 : (v3 ? 3 : 0));
        key |= m << (j << 1);
    }
    keys[row] = (u8)key;
    atomicAdd(&lcnt[key], 1);
    __syncthreads();
    if (lcnt[tid]) atomicAdd(&counters[tid], lcnt[tid]);
}

// ---------------------------------------------------------------------------
// scan: perm bases + tile table
// ---------------------------------------------------------------------------
__global__ __launch_bounds__(256) void scan_kernel(const int* __restrict__ counters,
                                                   int* __restrict__ cursors,
                                                   int4* __restrict__ tileInfo)
{
    __shared__ int sbuf[256];
    __shared__ int tot;
    int tid = threadIdx.x;
    int c = counters[tid];
    sbuf[tid] = c;
    __syncthreads();
    for (int off = 1; off < 256; off <<= 1) {
        int v = (tid >= off) ? sbuf[tid - off] : 0;
        __syncthreads();
        sbuf[tid] += v;
        __syncthreads();
    }
    int base = sbuf[tid] - c;
    cursors[tid] = base;
    int tiles = (c + 63) >> 6;
    __syncthreads();
    sbuf[tid] = tiles;
    __syncthreads();
    for (int off = 1; off < 256; off <<= 1) {
        int v = (tid >= off) ? sbuf[tid - off] : 0;
        __syncthreads();
        sbuf[tid] += v;
        __syncthreads();
    }
    int tbase = sbuf[tid] - tiles;
    if (tid == 255) tot = sbuf[255];
    __syncthreads();
    for (int t = 0; t < tiles; t++) {
        int rem = c - t * 64;
        tileInfo[tbase + t] = make_int4(tid, base + t * 64, rem > 64 ? 64 : rem, 0);
    }
    for (int i = tot + tid; i < MAXTILE; i += 256)
        tileInfo[i] = make_int4(0, 0, 0, 0);
}

// ---------------------------------------------------------------------------
// prepB: scatter rows into perm
// ---------------------------------------------------------------------------
__global__ __launch_bounds__(256) void prepB_kernel(const u8* __restrict__ keys,
                                                    int* __restrict__ cursors,
                                                    int* __restrict__ perm)
{
    __shared__ int lcnt[256];
    __shared__ int lbase[256];
    int tid = threadIdx.x;
    lcnt[tid] = 0;
    __syncthreads();
    int row = (blockIdx.x << 8) + tid;
    int key = keys[row];
    int loc = atomicAdd(&lcnt[key], 1);
    __syncthreads();
    if (lcnt[tid]) lbase[tid] = atomicAdd(&cursors[tid], lcnt[tid]);
    __syncthreads();
    perm[lbase[key] + loc] = row;
}

// ---------------------------------------------------------------------------
// repack: weights -> A-fragment layout [..][s][mt][lane][8] via LDS bounce.
//   A[m-row = out-col (lane&15)][k = in-feat (quad*8+j)] = W[k][out-col]
// blocks: [0,32) W01 | [32,224) Wpost1..3 | [224,240) pre | [240,244) fin | 244 bias
// ---------------------------------------------------------------------------
struct RepArgs {
    const void* W01; const void* Wp[3]; const void* pre[4]; const void* fin;
    const void* bias[9];
    u16 *rPre, *rW01, *rWp[3], *rFin, *cbias;
};

__global__ __launch_bounds__(256) void repack_kernel(const int* __restrict__ flagp, RepArgs R)
{
    __shared__ u16 T[8192];
    int flag = *flagp;
    int tid = threadIdx.x;
    int b = blockIdx.x;

    const void* src = nullptr; u16* dst = nullptr; int K = 0, k0 = 0, mrow = 0;
    if (b < 32) {
        int m = b >> 3, s = b & 7;
        src = R.W01; dst = R.rW01 + (m * 8 + s) * 8192; K = 256; k0 = s * 32; mrow = m;
    } else if (b < 224) {
        int idx = b - 32, mat = idx >> 6, r = idx & 63, m = r >> 4, s = r & 15;
        src = R.Wp[mat]; dst = R.rWp[mat] + (m * 16 + s) * 8192; K = 512; k0 = s * 32; mrow = m;
    } else if (b < 240) {
        int idx = b - 224, mat = idx >> 2, m = idx & 3;
        src = R.pre[mat]; dst = R.rPre + (mat * 4 + m) * 8192; K = 32; k0 = 0; mrow = m;
    } else if (b < 244) {
        // Wfin [m][256][8] -> [m][s8][lane][8], rows l16>=8 zero
        int m = b - 240;
        const u16* s16 = (const u16*)R.fin;
        const float* s32 = (const float*)R.fin;
        for (int i = tid; i < 2048; i += 256) {
            int si = (m * 256 + (i >> 3)) * 8 + (i & 7);
            T[i] = flag ? s16[si] : f2bf(s32[si]);
        }
        __syncthreads();
        u16* d = R.rFin + m * 4096;
        for (int i = tid; i < 4096; i += 256) {
            int s = i >> 9, lane = (i >> 3) & 63, j = i & 7;
            int q = lane >> 4, l16 = lane & 15;
            int k = s * 32 + q * 8 + j;
            d[i] = (l16 < 8) ? T[k * 8 + l16] : (u16)0;
        }
        return;
    } else {
        // biases -> cbias bf16. layout: node*2048 (pre) / +1024 (post); bfin @8192
        const int sz[9] = {1024,1024,1024,1024,1024,1024,1024,1024,32};
        const int of[9] = {0,1024,2048,3072,4096,5120,6144,7168,8192};
        for (int i = tid; i < 8224; i += 256) {
            int t = i, e = 0;
            while (t >= sz[e]) { t -= sz[e]; e++; }
            R.cbias[of[e] + t] = flag ? ((const u16*)R.bias[e])[t]
                                      : f2bf(((const float*)R.bias[e])[t]);
        }
        return;
    }

    const u16* s16 = (const u16*)src;
    const float* s32 = (const float*)src;
    // load 32k x 256n tile coalesced
    for (int i = tid; i < 8192; i += 256) {
        int k = i >> 8, n = i & 255;
        int srcIdx = (mrow * K + k0 + k) * 256 + n;
        T[i] = flag ? s16[srcIdx] : f2bf(s32[srcIdx]);
    }
    __syncthreads();
    for (int i = tid; i < 8192; i += 256) {
        int mt = i >> 9, lane = (i >> 3) & 63, j = i & 7;
        int k = ((lane >> 4) << 3) + j, n = (mt << 4) + (lane & 15);
        dst[i] = T[(k << 8) + n];
    }
}

// ---------------------------------------------------------------------------
// main: one block = 64 rows through the whole net, T-formulation.
// 8 waves; wave w: m-tiles {2w,2w+1} (32 out-cols) x 4 n-tiles (64 batch).
// xh = [batch 64][x 0..255 | hp 256..511 | pad] in LDS; b64 writes / b128 reads.
// ---------------------------------------------------------------------------
struct MainP { const u16 *rPre, *rW01, *rWp1, *rWp2, *rWp3, *rFin, *cbias; };

__global__ __launch_bounds__(512, 4) void main_kernel(
    const void* __restrict__ inRaw, const int* __restrict__ flagp,
    const int* __restrict__ perm, const int4* __restrict__ tileInfo,
    MainP P, void* __restrict__ outp)
{
    __shared__ __align__(16) u16 xh[64 * XHS];
    __shared__ int rowids[64];

    int tid = threadIdx.x;
    int lane = tid & 63, w = tid >> 6, quad = lane >> 4, l16 = lane & 15;

    int4 ti = tileInfo[blockIdx.x];
    int key = ti.x, ppos = ti.y, cntIn = ti.z;
    if (cntIn <= 0) return;
    int flag = *flagp;

    if (tid < 64) {
        int g = tid < cntIn ? tid : cntIn - 1;   // clamp partial tile (dups benign)
        rowids[tid] = perm[ppos + g];
    }
    __syncthreads();
    int rows[4];
#pragma unroll
    for (int nt = 0; nt < 4; nt++) rows[nt] = rowids[nt * 16 + l16];

    const u16* mainW[4] = {P.rW01, P.rWp1, P.rWp2, P.rWp3};
    const u16* in16 = (const u16*)inRaw;
    const float* in32 = (const float*)inRaw;

    for (int node = 0; node < 4; node++) {
        int m = (key >> (node << 1)) & 3;

        // ---- input B-frags: 8 consecutive feats of each batch row
        s8v fb[4];
#pragma unroll
        for (int nt = 0; nt < 4; nt++) {
            int off = rows[nt] * 144 + (node << 5) + (quad << 3);
            if (flag) fb[nt] = ld8(in16 + off);
            else {
                f4v f0 = *(const f4v*)(in32 + off);
                f4v f1 = *(const f4v*)(in32 + off + 4);
                s8v r;
#pragma unroll
                for (int j = 0; j < 4; j++) { r[j] = (short)f2bf(f0[j]); r[4 + j] = (short)f2bf(f1[j]); }
                fb[nt] = r;
            }
        }

        // ---- hp^T = relu(Wpre^T @ feats^T + bpre), K=32, write to xh[.,256..511]
        const u16* preB = P.rPre + ((node << 2) + m) * 8192;
#pragma unroll
        for (int ci = 0; ci < 2; ci++) {
            int mt = (w << 1) + ci;
            s8v a = ld8(preB + mt * 512 + lane * 8);
            u16x4 bv = *(const u16x4*)(P.cbias + node * 2048 + m * 256 + mt * 16 + quad * 4);
            f4v bias;
#pragma unroll
            for (int r = 0; r < 4; r++) bias[r] = bf2f(bv[r]);
#pragma unroll
            for (int nt = 0; nt < 4; nt++) {
                f4v c = MFMA16(a, fb[nt], bias);
                s4v p;
#pragma unroll
                for (int r = 0; r < 4; r++) { float v = c[r] > 0.f ? c[r] : 0.f; p[r] = (short)f2bf(v); }
                *(s4v*)&xh[(nt * 16 + l16) * XHS + 256 + mt * 16 + quad * 4] = p;
            }
        }
        __syncthreads();

        // ---- main GEMM: acc^T = W^T @ [x; hp]^T, K=512 (node0: hp-only K=256)
        int s0 = node ? 0 : 8;
        const u16* WB = mainW[node] + m * (node ? 16 : 8) * 8192;
        f4v acc[2][4];
        {
            u16x4 b0 = *(const u16x4*)(P.cbias + node * 2048 + 1024 + m * 256 + ((w << 1) + 0) * 16 + quad * 4);
            u16x4 b1 = *(const u16x4*)(P.cbias + node * 2048 + 1024 + m * 256 + ((w << 1) + 1) * 16 + quad * 4);
            f4v f0, f1;
#pragma unroll
            for (int r = 0; r < 4; r++) { f0[r] = bf2f(b0[r]); f1[r] = bf2f(b1[r]); }
#pragma unroll
            for (int nt = 0; nt < 4; nt++) { acc[0][nt] = f0; acc[1][nt] = f1; }
        }
        {
            s8v A0 = ld8(WB + (w << 1) * 512 + lane * 8);
            s8v A1 = ld8(WB + ((w << 1) + 1) * 512 + lane * 8);
#pragma unroll
            for (int s = s0; s < 16; s++) {
                s8v nA0 = A0, nA1 = A1;
                if (s + 1 < 16) {
                    const u16* nb = WB + (s + 1 - s0) * 8192;
                    nA0 = ld8(nb + (w << 1) * 512 + lane * 8);
                    nA1 = ld8(nb + ((w << 1) + 1) * 512 + lane * 8);
                }
#pragma unroll
                for (int nt = 0; nt < 4; nt++) {
                    s8v B = ld8(&xh[(nt * 16 + l16) * XHS + s * 32 + quad * 8]);
                    acc[0][nt] = MFMA16(A0, B, acc[0][nt]);
                    acc[1][nt] = MFMA16(A1, B, acc[1][nt]);
                }
                A0 = nA0;   // commit prefetch (the round-4 bug: these were dropped)
                A1 = nA1;
            }
        }
        __syncthreads();

        // ---- relu + pack + write hq^T into xh[.,0..255]
#pragma unroll
        for (int ci = 0; ci < 2; ci++) {
            int mt = (w << 1) + ci;
#pragma unroll
            for (int nt = 0; nt < 4; nt++) {
                s4v p;
#pragma unroll
                for (int r = 0; r < 4; r++) {
                    float v = acc[ci][nt][r]; v = v > 0.f ? v : 0.f;
                    p[r] = (short)f2bf(v);
                }
                *(s4v*)&xh[(nt * 16 + l16) * XHS + mt * 16 + quad * 4] = p;
            }
        }
    }
    __syncthreads();

    // ---- final: out^T = Wfin^T @ x3^T + bfin (waves 0..3, nt = w)
    if (w < 4) {
        int m3 = (key >> 6) & 3;
        f4v c;
#pragma unroll
        for (int r = 0; r < 4; r++)
            c[r] = (quad < 2) ? bf2f(P.cbias[8192 + m3 * 8 + quad * 4 + r]) : 0.f;
#pragma unroll
        for (int s = 0; s < 8; s++) {
            s8v A = ld8(P.rFin + m3 * 4096 + s * 512 + lane * 8);
            s8v B = ld8(&xh[(w * 16 + l16) * XHS + s * 32 + quad * 8]);
            c = MFMA16(A, B, c);
        }
        int bidx = w * 16 + l16;
        if (quad < 2 && bidx < cntIn) {
            int row = rowids[bidx];
            if (flag) {
                s4v p;
#pragma unroll
                for (int r = 0; r < 4; r++) p[r] = (short)f2bf(c[r]);
                *(s4v*)((u16*)outp + row * 8 + quad * 4) = p;
            } else {
                *(f4v*)((float*)outp + row * 8 + quad * 4) = c;
            }
        }
    }
}

// ---------------------------------------------------------------------------
extern "C" void kernel_launch(void* const* d_in, const int* in_sizes, int n_in,
                              void* d_out, int out_size, void* d_ws, size_t ws_size,
                              hipStream_t stream)
{
    (void)in_sizes; (void)n_in; (void)out_size;
    const void* input  = d_in[0];
    const void* W00    = d_in[1];
    const void* b00    = d_in[2];
    const void* W01    = d_in[3];
    const void* b01    = d_in[4];
    const void* Wpre1  = d_in[5];
    const void* bpre1  = d_in[6];
    const void* Wpost1 = d_in[7];
    const void* bpost1 = d_in[8];
    const void* Wpre2  = d_in[9];
    const void* bpre2  = d_in[10];
    const void* Wpost2 = d_in[11];
    const void* bpost2 = d_in[12];
    const void* Wpre3  = d_in[13];
    const void* bpre3  = d_in[14];
    const void* Wpost3 = d_in[15];
    const void* bpost3 = d_in[16];
    const void* Wfin   = d_in[17];
    const void* bfin   = d_in[18];

    char* base = (char*)d_ws;
    size_t off = 0;
    auto alloc = [&](size_t bytes) -> char* {
        char* p = base + off;
        off += (bytes + 255) & ~(size_t)255;
        return p;
    };
    int*  flagp    = (int*)alloc(4);
    int*  counters = (int*)alloc(256 * 4);
    int*  cursors  = (int*)alloc(256 * 4);
    u8*   keys     = (u8*)alloc(NB);
    int4* tileInfo = (int4*)alloc(MAXTILE * 16);
    int*  perm     = (int*)alloc((size_t)NB * 4);
    u16*  cbias    = (u16*)alloc(8224 * 2);
    u16*  rPre     = (u16*)alloc(131072 * 2);     // [node][m][mt][lane][8]
    u16*  rW01     = (u16*)alloc(262144 * 2);     // [m][s8][mt][lane][8]
    u16*  rWp1     = (u16*)alloc(524288 * 2);     // [m][s16][mt][lane][8]
    u16*  rWp2     = (u16*)alloc(524288 * 2);
    u16*  rWp3     = (u16*)alloc(524288 * 2);
    u16*  rFin     = (u16*)alloc(16384 * 2);      // [m][s8][lane][8]
    if (off > ws_size) return;

    probe_kernel<<<1, 256, 0, stream>>>(input, flagp, counters);
    prepA_kernel<<<128, 256, 0, stream>>>(input, flagp, counters, keys);
    scan_kernel<<<1, 256, 0, stream>>>(counters, cursors, tileInfo);
    prepB_kernel<<<128, 256, 0, stream>>>(keys, cursors, perm);

    RepArgs R;
    R.W01 = W01; R.Wp[0] = Wpost1; R.Wp[1] = Wpost2; R.Wp[2] = Wpost3;
    R.pre[0] = W00; R.pre[1] = Wpre1; R.pre[2] = Wpre2; R.pre[3] = Wpre3;
    R.fin = Wfin;
    R.bias[0] = b00;   R.bias[1] = b01;
    R.bias[2] = bpre1; R.bias[3] = bpost1;
    R.bias[4] = bpre2; R.bias[5] = bpost2;
    R.bias[6] = bpre3; R.bias[7] = bpost3;
    R.bias[8] = bfin;
    R.rPre = rPre; R.rW01 = rW01;
    R.rWp[0] = rWp1; R.rWp[1] = rWp2; R.rWp[2] = rWp3;
    R.rFin = rFin; R.cbias = cbias;
    repack_kernel<<<245, 256, 0, stream>>>(flagp, R);

    MainP P;
    P.rPre = rPre; P.rW01 = rW01; P.rWp1 = rWp1; P.rWp2 = rWp2; P.rWp3 = rWp3;
    P.rFin = rFin; P.cbias = cbias;
    main_kernel<<<MAXTILE, 512, 0, stream>>>(input, flagp, perm, tileInfo, P, d_out);
}